// Round 11
// baseline (629.752 us; speedup 1.0000x reference)
//
#include <hip/hip_runtime.h>

// ---------------------------------------------------------------------------
// Graph U-Net (GCN + SAGPool encoder / unpool decoder) on MI355X, fp32.
// Round 10: scratch fix confirmed (393 us, all our kernels < 40 us; top-5 is
// now the harness's 268MB ws re-poison). Pipeline is ~35 serial launches ->
// launch-count reduction package (35 -> 29), numerics-preserving:
//  - single-kernel exact topk (count+place merged; rank buffer gone)
//  - colsum_final fused into spmm (same mod-4 bucket association, bit-identical)
//  - vec_total fused into matvec_bits (same 256-stride+tree association)
// ---------------------------------------------------------------------------

constexpr int NN  = 4096;
constexpr int EE  = 65536;
constexpr int FIN = 500;
constexpr int KK1 = 3277, KK2 = 2622, KK3 = 2098;
constexpr int W0  = 128;               // words per A0 bit-row
constexpr int W1  = (KK1 + 31) / 32;   // 103
constexpr int W2  = (KK2 + 31) / 32;   // 82
constexpr int CAP = 2048;              // max tracked degree (theory max ~1300)

// -------------------------------- utility ----------------------------------

__global__ void fill4_kernel(float4* p, long n4) {
  long i = (long)blockIdx.x * blockDim.x + threadIdx.x;
  long stride = (long)gridDim.x * blockDim.x;
  float4 z = make_float4(0.f, 0.f, 0.f, 0.f);
  for (; i < n4; i += stride) p[i] = z;
}

__global__ void scatter_bits_kernel(unsigned* Ab, const int* __restrict__ ei) {
  int e = blockIdx.x * 256 + threadIdx.x;
  if (e < EE) {
    int src = ei[e], dst = ei[EE + e];
    atomicOr(&Ab[(size_t)dst * W0 + (src >> 5)], 1u << (src & 31));
  }
  if (e < NN) atomicOr(&Ab[(size_t)e * W0 + (e >> 5)], 1u << (e & 31));
}

__global__ void popcnt_dis_kernel(const unsigned* __restrict__ bits, int Wd,
                                  float* dis, int M) {
  int lane = threadIdx.x & 63;
  int row = blockIdx.x * 4 + (threadIdx.x >> 6);
  if (row >= M) return;
  const unsigned* rb = bits + (size_t)row * Wd;
  int c = 0;
  for (int w = lane; w < Wd; w += 64) c += __popc(rb[w]);
  for (int off = 32; off; off >>= 1) c += __shfl_down(c, off, 64);
  if (!lane) dis[row] = c > 0 ? rsqrtf((float)c) : 0.f;
}

// ---- SpMM over bitset adjacency, neighbor-list staged in LDS --------------
// basePart != null (complement mode): base[lane] = mod-4-bucket sum of
// basePart[g*64+lane] over g<baseG (bit-identical to the old colsum_final),
// then v = rs[row]*(base - bits_row@B) + bias; else v = rs[row]*(bits_row@B)+bias.
__global__ void spmm_nbr_kernel(const unsigned* __restrict__ bits, int Wd,
                                const float* __restrict__ B,
                                const float* __restrict__ basePart, int baseG,
                                const float* __restrict__ rowscale,
                                const float* __restrict__ bias,
                                const float* __restrict__ wrel,
                                const float* __restrict__ wroot,
                                float* __restrict__ tvec, float* __restrict__ rvec,
                                const int* __restrict__ sperm,
                                const float* __restrict__ sscale,
                                float* __restrict__ C, int M, int relu) {
  __shared__ int nbr[4][CAP];
  __shared__ int cnt[4];
  int lane = threadIdx.x & 63, wv = threadIdx.x >> 6;
  int row = blockIdx.x * 4 + wv;
  if (threadIdx.x < 4) cnt[threadIdx.x] = 0;
  __syncthreads();
  if (row < M) {
    const unsigned* rb = bits + (size_t)row * Wd;
    for (int w = lane; w < Wd; w += 64) {
      unsigned m = rb[w];
      while (m) {
        int b = __ffs(m) - 1;
        m &= m - 1;
        int idx = atomicAdd(&cnt[wv], 1);
        if (idx < CAP) nbr[wv][idx] = (w << 5) + b;
      }
    }
  }
  __syncthreads();
  if (row >= M) return;
  int nc = cnt[wv];
  float acc;
  if (nc <= CAP) {
    const int* lst = nbr[wv];
    float a0 = 0.f, a1 = 0.f, a2 = 0.f, a3 = 0.f;
    int q = 0;
    for (; q + 8 <= nc; q += 8) {
      int j0 = lst[q],     j1 = lst[q + 1], j2 = lst[q + 2], j3 = lst[q + 3];
      int j4 = lst[q + 4], j5 = lst[q + 5], j6 = lst[q + 6], j7 = lst[q + 7];
      float v0 = B[(size_t)j0 * 64 + lane], v1 = B[(size_t)j1 * 64 + lane];
      float v2 = B[(size_t)j2 * 64 + lane], v3 = B[(size_t)j3 * 64 + lane];
      float v4 = B[(size_t)j4 * 64 + lane], v5 = B[(size_t)j5 * 64 + lane];
      float v6 = B[(size_t)j6 * 64 + lane], v7 = B[(size_t)j7 * 64 + lane];
      a0 += v0 + v4; a1 += v1 + v5; a2 += v2 + v6; a3 += v3 + v7;
    }
    for (; q < nc; q++) a0 += B[(size_t)lst[q] * 64 + lane];
    acc = (a0 + a1) + (a2 + a3);
  } else {  // overflow fallback (not expected): serial bitscan
    const unsigned* rb = bits + (size_t)row * Wd;
    float a = 0.f;
    for (int w = 0; w < Wd; w++) {
      unsigned m = rb[w];
      while (m) {
        int b = __ffs(m) - 1;
        m &= m - 1;
        a += B[(size_t)((w << 5) + b) * 64 + lane];
      }
    }
    acc = a;
  }
  if (basePart) {
    float s0 = 0.f, s1 = 0.f, s2 = 0.f, s3 = 0.f;
    for (int g = 0; g < baseG; g += 4) s0 += basePart[(size_t)g * 64 + lane];
    for (int g = 1; g < baseG; g += 4) s1 += basePart[(size_t)g * 64 + lane];
    for (int g = 2; g < baseG; g += 4) s2 += basePart[(size_t)g * 64 + lane];
    for (int g = 3; g < baseG; g += 4) s3 += basePart[(size_t)g * 64 + lane];
    float base = ((s0 + s1) + s2) + s3;   // == old colsum_final association
    acc = base - acc;
  }
  float v = acc * rowscale[row];
  if (bias) v += bias[lane];
  if (relu) v = fmaxf(v, 0.f);
  if (sperm) {
    int p = sperm[row];
    C[(size_t)p * 64 + lane] = v * sscale[p];
  } else {
    C[(size_t)row * 64 + lane] = v;
  }
  if (wrel) {
    float t1 = v * wrel[lane], t2 = v * wroot[lane];
    for (int off = 32; off; off >>= 1) {
      t1 += __shfl_down(t1, off, 64);
      t2 += __shfl_down(t2, off, 64);
    }
    if (!lane) { tvec[row] = t1; rvec[row] = t2; }
  }
}

// s[row] = (useTotal ? tot - sum : sum){t[j] : j in bits(row)} + brel + rv[row]
// useTotal: tot = block-local reduce over t[0..M) replicating the old
// vec_total kernel's exact association (256-stride partials + halving tree).
__global__ void matvec_bits_kernel(const unsigned* __restrict__ bits, int Wd,
                                   const float* __restrict__ t,
                                   const float* __restrict__ rv,
                                   const float* __restrict__ brel,
                                   int useTotal,
                                   float* __restrict__ s, int M) {
  __shared__ float red[256];
  float tot = 0.f;
  if (useTotal) {
    float a = 0.f;
    for (int i = threadIdx.x; i < M; i += 256) a += t[i];
    red[threadIdx.x] = a;
    __syncthreads();
    for (int o = 128; o; o >>= 1) {
      if (threadIdx.x < o) red[threadIdx.x] += red[threadIdx.x + o];
      __syncthreads();
    }
    tot = red[0];
    __syncthreads();
  }
  int lane = threadIdx.x & 63;
  int row = blockIdx.x * 4 + (threadIdx.x >> 6);
  if (row >= M) return;
  const unsigned* rb = bits + (size_t)row * Wd;
  float acc = 0.f;
  for (int w = lane; w < Wd; w += 64) {
    unsigned m = rb[w];
    while (m) {
      int b = __ffs(m) - 1;
      m &= m - 1;
      acc += t[(w << 5) + b];
    }
  }
  for (int off = 32; off; off >>= 1) acc += __shfl_down(acc, off, 64);
  if (!lane) {
    float r0 = useTotal ? tot - acc : acc;
    s[row] = r0 + brel[0] + rv[row];
  }
}

// ---- exact jax.lax.top_k in ONE kernel: rank = #{s_j>s_i} + #{j<i: s_j==s_i}
__global__ void topk_kernel(const float* __restrict__ s, int n, int k,
                            int* __restrict__ perm, float* __restrict__ vals) {
  __shared__ float sh[4096];
  for (int j = threadIdx.x; j < n; j += 256) sh[j] = s[j];
  __syncthreads();
  int i = blockIdx.x * 256 + threadIdx.x;
  if (i >= n) return;
  float si = sh[i];
  int cnt = 0;
  int j = 0;
  for (; j + 4 <= n; j += 4) {
    float a = sh[j], b = sh[j + 1], c = sh[j + 2], d = sh[j + 3];
    cnt += (a > si || (a == si && j     < i)) ? 1 : 0;
    cnt += (b > si || (b == si && j + 1 < i)) ? 1 : 0;
    cnt += (c > si || (c == si && j + 2 < i)) ? 1 : 0;
    cnt += (d > si || (d == si && j + 3 < i)) ? 1 : 0;
  }
  for (; j < n; j++) {
    float a = sh[j];
    cnt += (a > si || (a == si && j < i)) ? 1 : 0;
  }
  if (cnt < k) { perm[cnt] = i; vals[cnt] = si; }
}

// up[perm[r]] = X[perm[r]] * tanh(vals[r]) * scale[perm[r]]
__global__ void scatter_gate_kernel(const float* __restrict__ X,
                                    const int* __restrict__ perm,
                                    const float* __restrict__ vals,
                                    const float* __restrict__ scale,
                                    float* up, int k) {
  int r = blockIdx.x * 4 + (threadIdx.x >> 6);
  int f = threadIdx.x & 63;
  if (r < k) {
    int p = perm[r];
    up[(size_t)p * 64 + f] = X[(size_t)p * 64 + f] * tanhf(vals[r]) * scale[p];
  }
}

// out[r] bits = { Ab[perm[r]] bit perm[c] : c in [0,K) }
__global__ void subgraph_bits_kernel(const unsigned* __restrict__ Ab, int WdIn,
                                     const int* __restrict__ perm, int K, int WdOut,
                                     unsigned* __restrict__ out) {
  __shared__ unsigned rowb[128];
  int r = blockIdx.x;
  const unsigned* src = Ab + (size_t)perm[r] * WdIn;
  for (int w = threadIdx.x; w < WdIn; w += 256) rowb[w] = src[w];
  __syncthreads();
  unsigned* ob = out + (size_t)r * WdOut;
  for (int c0 = 0; c0 < WdOut * 32; c0 += 256) {
    int c = c0 + threadIdx.x;
    bool pred = false;
    if (c < K) {
      int pc = perm[c];
      pred = (rowb[pc >> 5] >> (pc & 31)) & 1u;
    }
    unsigned long long m = __ballot(pred);
    if ((threadIdx.x & 63) == 0) {
      int wb = (c0 >> 5) + ((threadIdx.x >> 6) << 1);
      if (wb < WdOut)     ob[wb]     = (unsigned)m;
      if (wb + 1 < WdOut) ob[wb + 1] = (unsigned)(m >> 32);
    }
  }
}

// row i of A^2>0 with fused popcount->dis and optional complement output
__global__ void augment_or_kernel(const unsigned* __restrict__ in,
                                  unsigned* __restrict__ out,
                                  unsigned* __restrict__ holes,
                                  float* __restrict__ dis, int Wd, int K) {
  __shared__ unsigned roww[128];
  __shared__ int nbr[CAP];
  __shared__ int cnt;
  __shared__ int pcred[128];
  int i = blockIdx.x;
  if (threadIdx.x == 0) cnt = 0;
  const unsigned* rin = in + (size_t)i * Wd;
  for (int w = threadIdx.x; w < Wd; w += 128) roww[w] = rin[w];
  __syncthreads();
  for (int w = threadIdx.x; w < Wd; w += 128) {
    unsigned m = roww[w];
    while (m) {
      int b = __ffs(m) - 1;
      m &= m - 1;
      int idx = atomicAdd(&cnt, 1);
      if (idx < CAP) nbr[idx] = w * 32 + b;
    }
  }
  __syncthreads();
  int nc = min(cnt, CAP);
  int pc = 0;
  for (int w = threadIdx.x; w < Wd; w += 128) {
    unsigned a0 = 0, a1 = 0, a2 = 0, a3 = 0;
    int q = 0;
    for (; q + 4 <= nc; q += 4) {
      a0 |= in[(size_t)nbr[q] * Wd + w];
      a1 |= in[(size_t)nbr[q + 1] * Wd + w];
      a2 |= in[(size_t)nbr[q + 2] * Wd + w];
      a3 |= in[(size_t)nbr[q + 3] * Wd + w];
    }
    for (; q < nc; q++) a0 |= in[(size_t)nbr[q] * Wd + w];
    unsigned acc = (a0 | a1) | (a2 | a3);
    pc += __popc(acc);
    if (out) out[(size_t)i * Wd + w] = acc;
    if (holes) {
      int valid = K - w * 32;
      unsigned mask = valid >= 32 ? 0xffffffffu : ((1u << valid) - 1u);
      holes[(size_t)i * Wd + w] = ~acc & mask;
    }
  }
  pcred[threadIdx.x] = pc;
  __syncthreads();
  for (int o = 64; o; o >>= 1) {
    if (threadIdx.x < o) pcred[threadIdx.x] += pcred[threadIdx.x + o];
    __syncthreads();
  }
  if (!threadIdx.x) dis[i] = pcred[0] > 0 ? rsqrtf((float)pcred[0]) : 0.f;
}

// ---- x @ w1, split-K=4 (125 each), 64x64 tile, thread 4x4 (scalars only) --
__global__ __launch_bounds__(256) void gemm500_kernel(
    const float* __restrict__ A, const float* __restrict__ B,
    float* __restrict__ part) {
  __shared__ float As[32][68];   // [k][row]
  __shared__ float Bs[32][68];   // [k][col]
  int tr = threadIdx.x >> 4, tc = threadIdx.x & 15;
  int row0 = blockIdx.x * 64;
  int k0 = blockIdx.y * 125;
  float c00 = 0.f, c01 = 0.f, c02 = 0.f, c03 = 0.f;
  float c10 = 0.f, c11 = 0.f, c12 = 0.f, c13 = 0.f;
  float c20 = 0.f, c21 = 0.f, c22 = 0.f, c23 = 0.f;
  float c30 = 0.f, c31 = 0.f, c32 = 0.f, c33 = 0.f;
  int ra = tr * 4, cb = tc * 4;
  for (int c0 = 0; c0 < 125; c0 += 32) {
    for (int l = threadIdx.x; l < 64 * 32; l += 256) {
      int r = l >> 5, kk = l & 31;
      int gk = c0 + kk;
      As[kk][r] = (gk < 125) ? A[(size_t)(row0 + r) * FIN + k0 + gk] : 0.f;
    }
    for (int l = threadIdx.x; l < 32 * 64; l += 256) {
      int kk = l >> 6, c = l & 63;
      int gk = c0 + kk;
      Bs[kk][c] = (gk < 125) ? B[(size_t)(k0 + gk) * 64 + c] : 0.f;
    }
    __syncthreads();
#pragma unroll
    for (int kk = 0; kk < 32; kk++) {
      float a0 = As[kk][ra + 0], a1 = As[kk][ra + 1];
      float a2 = As[kk][ra + 2], a3 = As[kk][ra + 3];
      float b0 = Bs[kk][cb + 0], b1 = Bs[kk][cb + 1];
      float b2 = Bs[kk][cb + 2], b3 = Bs[kk][cb + 3];
      c00 += a0 * b0; c01 += a0 * b1; c02 += a0 * b2; c03 += a0 * b3;
      c10 += a1 * b0; c11 += a1 * b1; c12 += a1 * b2; c13 += a1 * b3;
      c20 += a2 * b0; c21 += a2 * b1; c22 += a2 * b2; c23 += a2 * b3;
      c30 += a3 * b0; c31 += a3 * b1; c32 += a3 * b2; c33 += a3 * b3;
    }
    __syncthreads();
  }
  float* P = part + (size_t)blockIdx.y * NN * 64;
  size_t base = (size_t)(row0 + ra) * 64 + cb;
  *(float4*)&P[base]            = make_float4(c00, c01, c02, c03);
  *(float4*)&P[base + 64]       = make_float4(c10, c11, c12, c13);
  *(float4*)&P[base + 128]      = make_float4(c20, c21, c22, c23);
  *(float4*)&P[base + 192]      = make_float4(c30, c31, c32, c33);
}

// xw[r][c] = (p0+p1+p2+p3)[r][c] * rowscale[r]
__global__ void reduce4_scale_kernel(const float4* __restrict__ part,
                                     const float* __restrict__ rowscale,
                                     float4* __restrict__ outp) {
  int e = blockIdx.x * 256 + threadIdx.x;   // float4 index; NN*16 total
  if (e >= NN * 16) return;
  float4 v0 = part[e];
  float4 v1 = part[e + NN * 16];
  float4 v2 = part[e + 2 * NN * 16];
  float4 v3 = part[e + 3 * NN * 16];
  float s = rowscale[e >> 4];
  float4 r;
  r.x = (v0.x + v1.x + v2.x + v3.x) * s;
  r.y = (v0.y + v1.y + v2.y + v3.y) * s;
  r.z = (v0.z + v1.z + v2.z + v3.z) * s;
  r.w = (v0.w + v1.w + v2.w + v3.w) * s;
  outp[e] = r;
}

// ---- K=64 GEMM, 16 rows/block, 4 acc/thread, broadcast A reads ------------
__global__ __launch_bounds__(256) void gemm_k64x4_kernel(
    const float* __restrict__ X, const float* __restrict__ B,
    const int* __restrict__ perm, const float* __restrict__ vals,
    const float* __restrict__ gscale, float* __restrict__ C, int M) {
  __shared__ float Bs[64][65];   // [k][c]
  __shared__ float As2[64][20];  // [k][p], p = (r&3)*4 + (r>>2)
  __shared__ int   srcs[16];
  __shared__ float gates[16];
  int t = threadIdx.x;
  int c = t & 63, g = t >> 6;
  int r0 = blockIdx.x * 16;
  if (t < 16) {
    int row = r0 + t;
    int src = 0; float gt = 1.f;
    if (row < M) {
      src = row;
      if (perm) { src = perm[row]; gt = tanhf(vals[row]) * gscale[row]; }
    }
    srcs[t] = src; gates[t] = gt;
  }
  for (int l = t; l < 64 * 64; l += 256) Bs[l >> 6][l & 63] = B[l];
  __syncthreads();
  for (int l = t; l < 16 * 64; l += 256) {
    int rr = l >> 6, k = l & 63;
    int p = (rr & 3) * 4 + (rr >> 2);
    As2[k][p] = (r0 + rr < M) ? X[(size_t)srcs[rr] * 64 + k] * gates[rr] : 0.f;
  }
  __syncthreads();
  float a0 = 0.f, a1 = 0.f, a2 = 0.f, a3 = 0.f;
  int gp = g * 4;
#pragma unroll
  for (int k = 0; k < 64; k++) {
    float x0 = As2[k][gp + 0], x1 = As2[k][gp + 1];
    float x2 = As2[k][gp + 2], x3 = As2[k][gp + 3];
    float bv = Bs[k][c];
    a0 += x0 * bv; a1 += x1 * bv; a2 += x2 * bv; a3 += x3 * bv;
  }
  if (r0 + g      < M) C[(size_t)(r0 + g)      * 64 + c] = a0;
  if (r0 + g + 4  < M) C[(size_t)(r0 + g + 4)  * 64 + c] = a1;
  if (r0 + g + 8  < M) C[(size_t)(r0 + g + 8)  * 64 + c] = a2;
  if (r0 + g + 12 < M) C[(size_t)(r0 + g + 12) * 64 + c] = a3;
}

// colsum partials: part[b][f] = sum of X[b*64 .. b*64+63][f]
__global__ void colsum_part_kernel(const float* __restrict__ X, int K,
                                   float* part) {
  __shared__ float red[4][64];
  int lane = threadIdx.x & 63, wv = threadIdx.x >> 6;
  int r0 = blockIdx.x * 64;
  float a = 0.f;
  for (int i = wv; i < 64; i += 4) {
    int r = r0 + i;
    if (r < K) a += X[(size_t)r * 64 + lane];
  }
  red[wv][lane] = a;
  __syncthreads();
  if (!wv)
    part[(size_t)blockIdx.x * 64 + lane] =
        red[0][lane] + red[1][lane] + red[2][lane] + red[3][lane];
}

// ---- final: C[4096 x 500] = Y[4096 x 64] @ W[64 x 500] + bias -------------
// 64x64 tile, thread 4x4, grid (64, 8), scalars only
__global__ __launch_bounds__(256) void gemm_wide_tile_kernel(
    const float* __restrict__ Y, const float* __restrict__ W,
    const float* __restrict__ bias, float* __restrict__ C) {
  __shared__ float Ys[64][68];   // [k][row]
  __shared__ float Ws[64][68];   // [k][col]
  int tr = threadIdx.x >> 4, tc = threadIdx.x & 15;
  int row0 = blockIdx.x * 64, c0 = blockIdx.y * 64;
  for (int l = threadIdx.x; l < 64 * 64; l += 256) {
    int r = l >> 6, k = l & 63;
    Ys[k][r] = Y[(size_t)(row0 + r) * 64 + k];
  }
  for (int l = threadIdx.x; l < 64 * 64; l += 256) {
    int k = l >> 6, cc = l & 63;
    int gc = c0 + cc;
    Ws[k][cc] = gc < FIN ? W[(size_t)k * FIN + gc] : 0.f;
  }
  __syncthreads();
  float c00 = 0.f, c01 = 0.f, c02 = 0.f, c03 = 0.f;
  float c10 = 0.f, c11 = 0.f, c12 = 0.f, c13 = 0.f;
  float c20 = 0.f, c21 = 0.f, c22 = 0.f, c23 = 0.f;
  float c30 = 0.f, c31 = 0.f, c32 = 0.f, c33 = 0.f;
  int ra = tr * 4, cb = tc * 4;
#pragma unroll
  for (int kk = 0; kk < 64; kk++) {
    float a0 = Ys[kk][ra + 0], a1 = Ys[kk][ra + 1];
    float a2 = Ys[kk][ra + 2], a3 = Ys[kk][ra + 3];
    float b0 = Ws[kk][cb + 0], b1 = Ws[kk][cb + 1];
    float b2 = Ws[kk][cb + 2], b3 = Ws[kk][cb + 3];
    c00 += a0 * b0; c01 += a0 * b1; c02 += a0 * b2; c03 += a0 * b3;
    c10 += a1 * b0; c11 += a1 * b1; c12 += a1 * b2; c13 += a1 * b3;
    c20 += a2 * b0; c21 += a2 * b1; c22 += a2 * b2; c23 += a2 * b3;
    c30 += a3 * b0; c31 += a3 * b1; c32 += a3 * b2; c33 += a3 * b3;
  }
  int row = row0 + ra;
  int gc0 = c0 + cb;
  // scalar stores with bounds check (last column tile is partial: 448+64>500)
  if (gc0 + 3 < FIN) {
    float b0 = bias[gc0], b1 = bias[gc0 + 1], b2 = bias[gc0 + 2], b3 = bias[gc0 + 3];
    float* p0 = &C[(size_t)row * FIN + gc0];
    p0[0] = c00 + b0; p0[1] = c01 + b1; p0[2] = c02 + b2; p0[3] = c03 + b3;
    float* p1 = p0 + FIN;
    p1[0] = c10 + b0; p1[1] = c11 + b1; p1[2] = c12 + b2; p1[3] = c13 + b3;
    float* p2 = p1 + FIN;
    p2[0] = c20 + b0; p2[1] = c21 + b1; p2[2] = c22 + b2; p2[3] = c23 + b3;
    float* p3 = p2 + FIN;
    p3[0] = c30 + b0; p3[1] = c31 + b1; p3[2] = c32 + b2; p3[3] = c33 + b3;
  } else {
    if (gc0 + 0 < FIN) { float bv = bias[gc0 + 0];
      C[(size_t)(row+0)*FIN+gc0+0]=c00+bv; C[(size_t)(row+1)*FIN+gc0+0]=c10+bv;
      C[(size_t)(row+2)*FIN+gc0+0]=c20+bv; C[(size_t)(row+3)*FIN+gc0+0]=c30+bv; }
    if (gc0 + 1 < FIN) { float bv = bias[gc0 + 1];
      C[(size_t)(row+0)*FIN+gc0+1]=c01+bv; C[(size_t)(row+1)*FIN+gc0+1]=c11+bv;
      C[(size_t)(row+2)*FIN+gc0+1]=c21+bv; C[(size_t)(row+3)*FIN+gc0+1]=c31+bv; }
    if (gc0 + 2 < FIN) { float bv = bias[gc0 + 2];
      C[(size_t)(row+0)*FIN+gc0+2]=c02+bv; C[(size_t)(row+1)*FIN+gc0+2]=c12+bv;
      C[(size_t)(row+2)*FIN+gc0+2]=c22+bv; C[(size_t)(row+3)*FIN+gc0+2]=c32+bv; }
    if (gc0 + 3 < FIN) { float bv = bias[gc0 + 3];
      C[(size_t)(row+0)*FIN+gc0+3]=c03+bv; C[(size_t)(row+1)*FIN+gc0+3]=c13+bv;
      C[(size_t)(row+2)*FIN+gc0+3]=c23+bv; C[(size_t)(row+3)*FIN+gc0+3]=c33+bv; }
  }
}

// ---------------------------------------------------------------------------

extern "C" void kernel_launch(void* const* d_in, const int* in_sizes, int n_in,
                              void* d_out, int out_size, void* d_ws, size_t ws_size,
                              hipStream_t stream) {
  const float* x      = (const float*)d_in[0];
  const float* w1     = (const float*)d_in[1];
  const float* b1     = (const float*)d_in[2];
  const float* w2     = (const float*)d_in[3];
  const float* b2     = (const float*)d_in[4];
  const float* w3     = (const float*)d_in[5];
  const float* b3     = (const float*)d_in[6];
  const float* p1wrel = (const float*)d_in[7];
  const float* p1brel = (const float*)d_in[8];
  const float* p1wroot= (const float*)d_in[9];
  const float* p2wrel = (const float*)d_in[10];
  const float* p2brel = (const float*)d_in[11];
  const float* p2wroot= (const float*)d_in[12];
  const float* p3wrel = (const float*)d_in[13];
  const float* p3brel = (const float*)d_in[14];
  const float* p3wroot= (const float*)d_in[15];
  const float* u0w    = (const float*)d_in[16];
  const float* u0b    = (const float*)d_in[17];
  const float* u1w    = (const float*)d_in[18];
  const float* u1b    = (const float*)d_in[19];
  const float* u2w    = (const float*)d_in[20];
  const float* u2b    = (const float*)d_in[21];
  const int*   ei     = (const int*)d_in[22];
  float* out = (float*)d_out;

  char* wp = (char*)d_ws;
  auto alloc = [&](size_t bytes) -> void* {
    void* p = (void*)wp;
    wp += (bytes + 255) & ~(size_t)255;
    return p;
  };
  // contiguous zero-fill span: A0b, up0, up1, up2
  unsigned* A0b  = (unsigned*)alloc((size_t)NN  * W0 * 4);
  float* up0  = (float*)alloc((size_t)KK2 * 64 * 4);
  float* up1  = (float*)alloc((size_t)KK1 * 64 * 4);
  float* up2  = (float*)alloc((size_t)NN * 64 * 4);
  char* zero_end = wp;
  unsigned* A1b  = (unsigned*)alloc((size_t)KK1 * W1 * 4);
  unsigned* A1ab = (unsigned*)alloc((size_t)KK1 * W1 * 4);
  unsigned* A2b  = (unsigned*)alloc((size_t)KK2 * W2 * 4);
  unsigned* H2b  = (unsigned*)alloc((size_t)KK2 * W2 * 4);
  float* dis0 = (float*)alloc((size_t)NN * 4);
  float* dis1 = (float*)alloc((size_t)KK1 * 4);
  float* dis2 = (float*)alloc((size_t)KK2 * 4);
  float* xw   = (float*)alloc((size_t)NN * 64 * 4);
  float* x1   = (float*)alloc((size_t)NN * 64 * 4);
  float* x2   = (float*)alloc((size_t)KK1 * 64 * 4);
  float* x3   = (float*)alloc((size_t)KK2 * 64 * 4);
  float* y0   = (float*)alloc((size_t)NN * 64 * 4);
  float* part500 = (float*)alloc((size_t)4 * NN * 64 * 4);
  float* tvec = (float*)alloc((size_t)NN * 4);
  float* rvec = (float*)alloc((size_t)NN * 4);
  float* svec = (float*)alloc((size_t)NN * 4);
  float* vals = (float*)alloc((size_t)NN * 4);
  float* part = (float*)alloc((size_t)64 * 64 * 4);
  int* perm1 = (int*)alloc((size_t)KK1 * 4);
  int* perm2 = (int*)alloc((size_t)KK2 * 4);
  int* perm3 = (int*)alloc((size_t)KK3 * 4);

  const int G2 = (KK2 + 63) / 64;   // colsum partial count (41)

  // ---- single zero-fill for all scattered-write buffers ----
  {
    long n4 = (long)(zero_end - (char*)A0b) / 16;
    fill4_kernel<<<2048, 256, 0, stream>>>((float4*)A0b, n4);
  }

  // ---- A0 bitset + dis0 ----
  scatter_bits_kernel<<<(EE + 255) / 256, 256, 0, stream>>>(A0b, ei);
  popcnt_dis_kernel<<<NN / 4, 256, 0, stream>>>(A0b, W0, dis0, NN);

  // ---- level 1 ----
  gemm500_kernel<<<dim3(64, 4), 256, 0, stream>>>(x, w1, part500);
  reduce4_scale_kernel<<<NN * 16 / 256, 256, 0, stream>>>(
      (const float4*)part500, dis0, (float4*)xw);
  spmm_nbr_kernel<<<NN / 4, 256, 0, stream>>>(A0b, W0, xw, nullptr, 0, dis0, b1,
      p1wrel, p1wroot, tvec, rvec, nullptr, nullptr, x1, NN, 0);
  matvec_bits_kernel<<<NN / 4, 256, 0, stream>>>(A0b, W0, tvec, rvec, p1brel, 0, svec, NN);
  topk_kernel<<<(NN + 255) / 256, 256, 0, stream>>>(svec, NN, KK1, perm1, vals);
  subgraph_bits_kernel<<<KK1, 256, 0, stream>>>(A0b, W0, perm1, KK1, W1, A1b);
  augment_or_kernel<<<KK1, 128, 0, stream>>>(A1b, A1ab, nullptr, dis1, W1, KK1);

  // ---- level 2 ----
  gemm_k64x4_kernel<<<(KK1 + 15) / 16, 256, 0, stream>>>(x1, w2, perm1, vals, dis1, xw, KK1);
  spmm_nbr_kernel<<<(KK1 + 3) / 4, 256, 0, stream>>>(A1ab, W1, xw, nullptr, 0, dis1, b2,
      p2wrel, p2wroot, tvec, rvec, nullptr, nullptr, x2, KK1, 0);
  matvec_bits_kernel<<<(KK1 + 3) / 4, 256, 0, stream>>>(A1ab, W1, tvec, rvec, p2brel, 0, svec, KK1);
  topk_kernel<<<(KK1 + 255) / 256, 256, 0, stream>>>(svec, KK1, KK2, perm2, vals);
  subgraph_bits_kernel<<<KK2, 256, 0, stream>>>(A1ab, W1, perm2, KK2, W2, A2b);
  // A2a ~99.98% dense: emit only complement (holes) + dis2
  augment_or_kernel<<<KK2, 128, 0, stream>>>(A2b, nullptr, H2b, dis2, W2, KK2);

  // ---- level 3 (complement trick: A2a@B = colsum(B) - holes@B) ----
  gemm_k64x4_kernel<<<(KK2 + 15) / 16, 256, 0, stream>>>(x2, w3, perm2, vals, dis2, xw, KK2);
  colsum_part_kernel<<<G2, 256, 0, stream>>>(xw, KK2, part);
  spmm_nbr_kernel<<<(KK2 + 3) / 4, 256, 0, stream>>>(H2b, W2, xw, part, G2, dis2, b3,
      p3wrel, p3wroot, tvec, rvec, nullptr, nullptr, x3, KK2, 0);
  matvec_bits_kernel<<<(KK2 + 3) / 4, 256, 0, stream>>>(H2b, W2, tvec, rvec, p3brel, 1, svec, KK2);
  topk_kernel<<<(KK2 + 255) / 256, 256, 0, stream>>>(svec, KK2, KK3, perm3, vals);
  scatter_gate_kernel<<<(KK3 + 3) / 4, 256, 0, stream>>>(x3, perm3, vals, dis2, up0, KK3);

  // ---- decoder ----
  gemm_k64x4_kernel<<<(KK2 + 15) / 16, 256, 0, stream>>>(up0, u0w, nullptr, nullptr, nullptr, xw, KK2);
  colsum_part_kernel<<<G2, 256, 0, stream>>>(xw, KK2, part);
  spmm_nbr_kernel<<<(KK2 + 3) / 4, 256, 0, stream>>>(H2b, W2, xw, part, G2, dis2, u0b,
      nullptr, nullptr, nullptr, nullptr, perm2, dis1, up1, KK2, 1);

  gemm_k64x4_kernel<<<(KK1 + 15) / 16, 256, 0, stream>>>(up1, u1w, nullptr, nullptr, nullptr, xw, KK1);
  spmm_nbr_kernel<<<(KK1 + 3) / 4, 256, 0, stream>>>(A1ab, W1, xw, nullptr, 0, dis1, u1b,
      nullptr, nullptr, nullptr, nullptr, perm1, dis0, up2, KK1, 1);

  // final GCN reassociated: out = (dis0 .* (A0 @ up2)) @ u2w + u2b
  spmm_nbr_kernel<<<NN / 4, 256, 0, stream>>>(A0b, W0, up2, nullptr, 0, dis0, nullptr,
      nullptr, nullptr, nullptr, nullptr, nullptr, nullptr, y0, NN, 0);
  gemm_wide_tile_kernel<<<dim3(64, 8), 256, 0, stream>>>(y0, u2w, u2b, out);
}

// Round 12
// 391.997 us; speedup vs baseline: 1.6065x; 1.6065x over previous
//
#include <hip/hip_runtime.h>

// ---------------------------------------------------------------------------
// Graph U-Net (GCN + SAGPool encoder / unpool decoder) on MI355X, fp32.
// Round 11: REVERT the fused single-kernel topk (117us x3 — 16 blocks, 0.7%
// occupancy, serial 4096-scan per thread) back to the measured-good 2-kernel
// 2D-split count + place (128+ blocks). rank zeroing stays fused in
// matvec_bits. Keep the two good round-10 fusions (colsum->spmm, vec_total->
// matvec). Launches 29 -> 32, but topk 351us -> ~20us.
// ---------------------------------------------------------------------------

constexpr int NN  = 4096;
constexpr int EE  = 65536;
constexpr int FIN = 500;
constexpr int KK1 = 3277, KK2 = 2622, KK3 = 2098;
constexpr int W0  = 128;               // words per A0 bit-row
constexpr int W1  = (KK1 + 31) / 32;   // 103
constexpr int W2  = (KK2 + 31) / 32;   // 82
constexpr int CAP = 2048;              // max tracked degree (theory max ~1300)

// -------------------------------- utility ----------------------------------

__global__ void fill4_kernel(float4* p, long n4) {
  long i = (long)blockIdx.x * blockDim.x + threadIdx.x;
  long stride = (long)gridDim.x * blockDim.x;
  float4 z = make_float4(0.f, 0.f, 0.f, 0.f);
  for (; i < n4; i += stride) p[i] = z;
}

__global__ void scatter_bits_kernel(unsigned* Ab, const int* __restrict__ ei) {
  int e = blockIdx.x * 256 + threadIdx.x;
  if (e < EE) {
    int src = ei[e], dst = ei[EE + e];
    atomicOr(&Ab[(size_t)dst * W0 + (src >> 5)], 1u << (src & 31));
  }
  if (e < NN) atomicOr(&Ab[(size_t)e * W0 + (e >> 5)], 1u << (e & 31));
}

__global__ void popcnt_dis_kernel(const unsigned* __restrict__ bits, int Wd,
                                  float* dis, int M) {
  int lane = threadIdx.x & 63;
  int row = blockIdx.x * 4 + (threadIdx.x >> 6);
  if (row >= M) return;
  const unsigned* rb = bits + (size_t)row * Wd;
  int c = 0;
  for (int w = lane; w < Wd; w += 64) c += __popc(rb[w]);
  for (int off = 32; off; off >>= 1) c += __shfl_down(c, off, 64);
  if (!lane) dis[row] = c > 0 ? rsqrtf((float)c) : 0.f;
}

// ---- SpMM over bitset adjacency, neighbor-list staged in LDS --------------
// basePart != null (complement mode): base[lane] = mod-4-bucket sum of
// basePart[g*64+lane] over g<baseG (bit-identical to old colsum_final),
// then v = rs[row]*(base - bits_row@B) + bias; else v = rs[row]*(bits_row@B)+bias.
__global__ void spmm_nbr_kernel(const unsigned* __restrict__ bits, int Wd,
                                const float* __restrict__ B,
                                const float* __restrict__ basePart, int baseG,
                                const float* __restrict__ rowscale,
                                const float* __restrict__ bias,
                                const float* __restrict__ wrel,
                                const float* __restrict__ wroot,
                                float* __restrict__ tvec, float* __restrict__ rvec,
                                const int* __restrict__ sperm,
                                const float* __restrict__ sscale,
                                float* __restrict__ C, int M, int relu) {
  __shared__ int nbr[4][CAP];
  __shared__ int cnt[4];
  int lane = threadIdx.x & 63, wv = threadIdx.x >> 6;
  int row = blockIdx.x * 4 + wv;
  if (threadIdx.x < 4) cnt[threadIdx.x] = 0;
  __syncthreads();
  if (row < M) {
    const unsigned* rb = bits + (size_t)row * Wd;
    for (int w = lane; w < Wd; w += 64) {
      unsigned m = rb[w];
      while (m) {
        int b = __ffs(m) - 1;
        m &= m - 1;
        int idx = atomicAdd(&cnt[wv], 1);
        if (idx < CAP) nbr[wv][idx] = (w << 5) + b;
      }
    }
  }
  __syncthreads();
  if (row >= M) return;
  int nc = cnt[wv];
  float acc;
  if (nc <= CAP) {
    const int* lst = nbr[wv];
    float a0 = 0.f, a1 = 0.f, a2 = 0.f, a3 = 0.f;
    int q = 0;
    for (; q + 8 <= nc; q += 8) {
      int j0 = lst[q],     j1 = lst[q + 1], j2 = lst[q + 2], j3 = lst[q + 3];
      int j4 = lst[q + 4], j5 = lst[q + 5], j6 = lst[q + 6], j7 = lst[q + 7];
      float v0 = B[(size_t)j0 * 64 + lane], v1 = B[(size_t)j1 * 64 + lane];
      float v2 = B[(size_t)j2 * 64 + lane], v3 = B[(size_t)j3 * 64 + lane];
      float v4 = B[(size_t)j4 * 64 + lane], v5 = B[(size_t)j5 * 64 + lane];
      float v6 = B[(size_t)j6 * 64 + lane], v7 = B[(size_t)j7 * 64 + lane];
      a0 += v0 + v4; a1 += v1 + v5; a2 += v2 + v6; a3 += v3 + v7;
    }
    for (; q < nc; q++) a0 += B[(size_t)lst[q] * 64 + lane];
    acc = (a0 + a1) + (a2 + a3);
  } else {  // overflow fallback (not expected): serial bitscan
    const unsigned* rb = bits + (size_t)row * Wd;
    float a = 0.f;
    for (int w = 0; w < Wd; w++) {
      unsigned m = rb[w];
      while (m) {
        int b = __ffs(m) - 1;
        m &= m - 1;
        a += B[(size_t)((w << 5) + b) * 64 + lane];
      }
    }
    acc = a;
  }
  if (basePart) {
    float s0 = 0.f, s1 = 0.f, s2 = 0.f, s3 = 0.f;
    for (int g = 0; g < baseG; g += 4) s0 += basePart[(size_t)g * 64 + lane];
    for (int g = 1; g < baseG; g += 4) s1 += basePart[(size_t)g * 64 + lane];
    for (int g = 2; g < baseG; g += 4) s2 += basePart[(size_t)g * 64 + lane];
    for (int g = 3; g < baseG; g += 4) s3 += basePart[(size_t)g * 64 + lane];
    float base = ((s0 + s1) + s2) + s3;   // == old colsum_final association
    acc = base - acc;
  }
  float v = acc * rowscale[row];
  if (bias) v += bias[lane];
  if (relu) v = fmaxf(v, 0.f);
  if (sperm) {
    int p = sperm[row];
    C[(size_t)p * 64 + lane] = v * sscale[p];
  } else {
    C[(size_t)row * 64 + lane] = v;
  }
  if (wrel) {
    float t1 = v * wrel[lane], t2 = v * wroot[lane];
    for (int off = 32; off; off >>= 1) {
      t1 += __shfl_down(t1, off, 64);
      t2 += __shfl_down(t2, off, 64);
    }
    if (!lane) { tvec[row] = t1; rvec[row] = t2; }
  }
}

// s[row] = (useTotal ? tot - sum : sum){t[j] : j in bits(row)} + brel + rv[row]
// useTotal: tot = block-local reduce over t[0..M) replicating the old
// vec_total kernel's exact association. Also zeroes rank[row].
__global__ void matvec_bits_kernel(const unsigned* __restrict__ bits, int Wd,
                                   const float* __restrict__ t,
                                   const float* __restrict__ rv,
                                   const float* __restrict__ brel,
                                   int useTotal,
                                   float* __restrict__ s,
                                   int* __restrict__ rankz, int M) {
  __shared__ float red[256];
  float tot = 0.f;
  if (useTotal) {
    float a = 0.f;
    for (int i = threadIdx.x; i < M; i += 256) a += t[i];
    red[threadIdx.x] = a;
    __syncthreads();
    for (int o = 128; o; o >>= 1) {
      if (threadIdx.x < o) red[threadIdx.x] += red[threadIdx.x + o];
      __syncthreads();
    }
    tot = red[0];
    __syncthreads();
  }
  int lane = threadIdx.x & 63;
  int row = blockIdx.x * 4 + (threadIdx.x >> 6);
  if (row >= M) return;
  const unsigned* rb = bits + (size_t)row * Wd;
  float acc = 0.f;
  for (int w = lane; w < Wd; w += 64) {
    unsigned m = rb[w];
    while (m) {
      int b = __ffs(m) - 1;
      m &= m - 1;
      acc += t[(w << 5) + b];
    }
  }
  for (int off = 32; off; off >>= 1) acc += __shfl_down(acc, off, 64);
  if (!lane) {
    float r0 = useTotal ? tot - acc : acc;
    s[row] = r0 + brel[0] + rv[row];
    rankz[row] = 0;
  }
}

// ---- top-k (exact lax.top_k order), 2D-split rank count (measured-good) ----
__global__ void topk_count_kernel(const float* __restrict__ s, int n, int* rank) {
  __shared__ float sh[512];
  int j0 = blockIdx.y * 512;
  for (int j = threadIdx.x; j < 512; j += 256) {
    int gj = j0 + j;
    sh[j] = gj < n ? s[gj] : 0.f;
  }
  __syncthreads();
  int i = blockIdx.x * 256 + threadIdx.x;
  if (i >= n) return;
  float si = s[i];
  int jmax = min(512, n - j0);
  int cnt = 0;
  for (int j = 0; j < jmax; j++) {
    float sj = sh[j];
    int gj = j0 + j;
    cnt += (sj > si || (sj == si && gj < i)) ? 1 : 0;
  }
  if (cnt) atomicAdd(&rank[i], cnt);
}

__global__ void topk_place_kernel(const float* __restrict__ s,
                                  const int* __restrict__ rank, int n, int k,
                                  int* perm, float* vals) {
  int i = blockIdx.x * 256 + threadIdx.x;
  if (i >= n) return;
  int rk = rank[i];
  if (rk < k) { perm[rk] = i; vals[rk] = s[i]; }
}

// up[perm[r]] = X[perm[r]] * tanh(vals[r]) * scale[perm[r]]
__global__ void scatter_gate_kernel(const float* __restrict__ X,
                                    const int* __restrict__ perm,
                                    const float* __restrict__ vals,
                                    const float* __restrict__ scale,
                                    float* up, int k) {
  int r = blockIdx.x * 4 + (threadIdx.x >> 6);
  int f = threadIdx.x & 63;
  if (r < k) {
    int p = perm[r];
    up[(size_t)p * 64 + f] = X[(size_t)p * 64 + f] * tanhf(vals[r]) * scale[p];
  }
}

// out[r] bits = { Ab[perm[r]] bit perm[c] : c in [0,K) }
__global__ void subgraph_bits_kernel(const unsigned* __restrict__ Ab, int WdIn,
                                     const int* __restrict__ perm, int K, int WdOut,
                                     unsigned* __restrict__ out) {
  __shared__ unsigned rowb[128];
  int r = blockIdx.x;
  const unsigned* src = Ab + (size_t)perm[r] * WdIn;
  for (int w = threadIdx.x; w < WdIn; w += 256) rowb[w] = src[w];
  __syncthreads();
  unsigned* ob = out + (size_t)r * WdOut;
  for (int c0 = 0; c0 < WdOut * 32; c0 += 256) {
    int c = c0 + threadIdx.x;
    bool pred = false;
    if (c < K) {
      int pc = perm[c];
      pred = (rowb[pc >> 5] >> (pc & 31)) & 1u;
    }
    unsigned long long m = __ballot(pred);
    if ((threadIdx.x & 63) == 0) {
      int wb = (c0 >> 5) + ((threadIdx.x >> 6) << 1);
      if (wb < WdOut)     ob[wb]     = (unsigned)m;
      if (wb + 1 < WdOut) ob[wb + 1] = (unsigned)(m >> 32);
    }
  }
}

// row i of A^2>0 with fused popcount->dis and optional complement output
__global__ void augment_or_kernel(const unsigned* __restrict__ in,
                                  unsigned* __restrict__ out,
                                  unsigned* __restrict__ holes,
                                  float* __restrict__ dis, int Wd, int K) {
  __shared__ unsigned roww[128];
  __shared__ int nbr[CAP];
  __shared__ int cnt;
  __shared__ int pcred[128];
  int i = blockIdx.x;
  if (threadIdx.x == 0) cnt = 0;
  const unsigned* rin = in + (size_t)i * Wd;
  for (int w = threadIdx.x; w < Wd; w += 128) roww[w] = rin[w];
  __syncthreads();
  for (int w = threadIdx.x; w < Wd; w += 128) {
    unsigned m = roww[w];
    while (m) {
      int b = __ffs(m) - 1;
      m &= m - 1;
      int idx = atomicAdd(&cnt, 1);
      if (idx < CAP) nbr[idx] = w * 32 + b;
    }
  }
  __syncthreads();
  int nc = min(cnt, CAP);
  int pc = 0;
  for (int w = threadIdx.x; w < Wd; w += 128) {
    unsigned a0 = 0, a1 = 0, a2 = 0, a3 = 0;
    int q = 0;
    for (; q + 4 <= nc; q += 4) {
      a0 |= in[(size_t)nbr[q] * Wd + w];
      a1 |= in[(size_t)nbr[q + 1] * Wd + w];
      a2 |= in[(size_t)nbr[q + 2] * Wd + w];
      a3 |= in[(size_t)nbr[q + 3] * Wd + w];
    }
    for (; q < nc; q++) a0 |= in[(size_t)nbr[q] * Wd + w];
    unsigned acc = (a0 | a1) | (a2 | a3);
    pc += __popc(acc);
    if (out) out[(size_t)i * Wd + w] = acc;
    if (holes) {
      int valid = K - w * 32;
      unsigned mask = valid >= 32 ? 0xffffffffu : ((1u << valid) - 1u);
      holes[(size_t)i * Wd + w] = ~acc & mask;
    }
  }
  pcred[threadIdx.x] = pc;
  __syncthreads();
  for (int o = 64; o; o >>= 1) {
    if (threadIdx.x < o) pcred[threadIdx.x] += pcred[threadIdx.x + o];
    __syncthreads();
  }
  if (!threadIdx.x) dis[i] = pcred[0] > 0 ? rsqrtf((float)pcred[0]) : 0.f;
}

// ---- x @ w1, split-K=4 (125 each), 64x64 tile, thread 4x4 (scalars only) --
__global__ __launch_bounds__(256) void gemm500_kernel(
    const float* __restrict__ A, const float* __restrict__ B,
    float* __restrict__ part) {
  __shared__ float As[32][68];   // [k][row]
  __shared__ float Bs[32][68];   // [k][col]
  int tr = threadIdx.x >> 4, tc = threadIdx.x & 15;
  int row0 = blockIdx.x * 64;
  int k0 = blockIdx.y * 125;
  float c00 = 0.f, c01 = 0.f, c02 = 0.f, c03 = 0.f;
  float c10 = 0.f, c11 = 0.f, c12 = 0.f, c13 = 0.f;
  float c20 = 0.f, c21 = 0.f, c22 = 0.f, c23 = 0.f;
  float c30 = 0.f, c31 = 0.f, c32 = 0.f, c33 = 0.f;
  int ra = tr * 4, cb = tc * 4;
  for (int c0 = 0; c0 < 125; c0 += 32) {
    for (int l = threadIdx.x; l < 64 * 32; l += 256) {
      int r = l >> 5, kk = l & 31;
      int gk = c0 + kk;
      As[kk][r] = (gk < 125) ? A[(size_t)(row0 + r) * FIN + k0 + gk] : 0.f;
    }
    for (int l = threadIdx.x; l < 32 * 64; l += 256) {
      int kk = l >> 6, c = l & 63;
      int gk = c0 + kk;
      Bs[kk][c] = (gk < 125) ? B[(size_t)(k0 + gk) * 64 + c] : 0.f;
    }
    __syncthreads();
#pragma unroll
    for (int kk = 0; kk < 32; kk++) {
      float a0 = As[kk][ra + 0], a1 = As[kk][ra + 1];
      float a2 = As[kk][ra + 2], a3 = As[kk][ra + 3];
      float b0 = Bs[kk][cb + 0], b1 = Bs[kk][cb + 1];
      float b2 = Bs[kk][cb + 2], b3 = Bs[kk][cb + 3];
      c00 += a0 * b0; c01 += a0 * b1; c02 += a0 * b2; c03 += a0 * b3;
      c10 += a1 * b0; c11 += a1 * b1; c12 += a1 * b2; c13 += a1 * b3;
      c20 += a2 * b0; c21 += a2 * b1; c22 += a2 * b2; c23 += a2 * b3;
      c30 += a3 * b0; c31 += a3 * b1; c32 += a3 * b2; c33 += a3 * b3;
    }
    __syncthreads();
  }
  float* P = part + (size_t)blockIdx.y * NN * 64;
  size_t base = (size_t)(row0 + ra) * 64 + cb;
  *(float4*)&P[base]            = make_float4(c00, c01, c02, c03);
  *(float4*)&P[base + 64]       = make_float4(c10, c11, c12, c13);
  *(float4*)&P[base + 128]      = make_float4(c20, c21, c22, c23);
  *(float4*)&P[base + 192]      = make_float4(c30, c31, c32, c33);
}

// xw[r][c] = (p0+p1+p2+p3)[r][c] * rowscale[r]
__global__ void reduce4_scale_kernel(const float4* __restrict__ part,
                                     const float* __restrict__ rowscale,
                                     float4* __restrict__ outp) {
  int e = blockIdx.x * 256 + threadIdx.x;   // float4 index; NN*16 total
  if (e >= NN * 16) return;
  float4 v0 = part[e];
  float4 v1 = part[e + NN * 16];
  float4 v2 = part[e + 2 * NN * 16];
  float4 v3 = part[e + 3 * NN * 16];
  float s = rowscale[e >> 4];
  float4 r;
  r.x = (v0.x + v1.x + v2.x + v3.x) * s;
  r.y = (v0.y + v1.y + v2.y + v3.y) * s;
  r.z = (v0.z + v1.z + v2.z + v3.z) * s;
  r.w = (v0.w + v1.w + v2.w + v3.w) * s;
  outp[e] = r;
}

// ---- K=64 GEMM, 16 rows/block, 4 acc/thread, broadcast A reads ------------
__global__ __launch_bounds__(256) void gemm_k64x4_kernel(
    const float* __restrict__ X, const float* __restrict__ B,
    const int* __restrict__ perm, const float* __restrict__ vals,
    const float* __restrict__ gscale, float* __restrict__ C, int M) {
  __shared__ float Bs[64][65];   // [k][c]
  __shared__ float As2[64][20];  // [k][p], p = (r&3)*4 + (r>>2)
  __shared__ int   srcs[16];
  __shared__ float gates[16];
  int t = threadIdx.x;
  int c = t & 63, g = t >> 6;
  int r0 = blockIdx.x * 16;
  if (t < 16) {
    int row = r0 + t;
    int src = 0; float gt = 1.f;
    if (row < M) {
      src = row;
      if (perm) { src = perm[row]; gt = tanhf(vals[row]) * gscale[row]; }
    }
    srcs[t] = src; gates[t] = gt;
  }
  for (int l = t; l < 64 * 64; l += 256) Bs[l >> 6][l & 63] = B[l];
  __syncthreads();
  for (int l = t; l < 16 * 64; l += 256) {
    int rr = l >> 6, k = l & 63;
    int p = (rr & 3) * 4 + (rr >> 2);
    As2[k][p] = (r0 + rr < M) ? X[(size_t)srcs[rr] * 64 + k] * gates[rr] : 0.f;
  }
  __syncthreads();
  float a0 = 0.f, a1 = 0.f, a2 = 0.f, a3 = 0.f;
  int gp = g * 4;
#pragma unroll
  for (int k = 0; k < 64; k++) {
    float x0 = As2[k][gp + 0], x1 = As2[k][gp + 1];
    float x2 = As2[k][gp + 2], x3 = As2[k][gp + 3];
    float bv = Bs[k][c];
    a0 += x0 * bv; a1 += x1 * bv; a2 += x2 * bv; a3 += x3 * bv;
  }
  if (r0 + g      < M) C[(size_t)(r0 + g)      * 64 + c] = a0;
  if (r0 + g + 4  < M) C[(size_t)(r0 + g + 4)  * 64 + c] = a1;
  if (r0 + g + 8  < M) C[(size_t)(r0 + g + 8)  * 64 + c] = a2;
  if (r0 + g + 12 < M) C[(size_t)(r0 + g + 12) * 64 + c] = a3;
}

// colsum partials: part[b][f] = sum of X[b*64 .. b*64+63][f]
__global__ void colsum_part_kernel(const float* __restrict__ X, int K,
                                   float* part) {
  __shared__ float red[4][64];
  int lane = threadIdx.x & 63, wv = threadIdx.x >> 6;
  int r0 = blockIdx.x * 64;
  float a = 0.f;
  for (int i = wv; i < 64; i += 4) {
    int r = r0 + i;
    if (r < K) a += X[(size_t)r * 64 + lane];
  }
  red[wv][lane] = a;
  __syncthreads();
  if (!wv)
    part[(size_t)blockIdx.x * 64 + lane] =
        red[0][lane] + red[1][lane] + red[2][lane] + red[3][lane];
}

// ---- final: C[4096 x 500] = Y[4096 x 64] @ W[64 x 500] + bias -------------
// 64x64 tile, thread 4x4, grid (64, 8), scalars only
__global__ __launch_bounds__(256) void gemm_wide_tile_kernel(
    const float* __restrict__ Y, const float* __restrict__ W,
    const float* __restrict__ bias, float* __restrict__ C) {
  __shared__ float Ys[64][68];   // [k][row]
  __shared__ float Ws[64][68];   // [k][col]
  int tr = threadIdx.x >> 4, tc = threadIdx.x & 15;
  int row0 = blockIdx.x * 64, c0 = blockIdx.y * 64;
  for (int l = threadIdx.x; l < 64 * 64; l += 256) {
    int r = l >> 6, k = l & 63;
    Ys[k][r] = Y[(size_t)(row0 + r) * 64 + k];
  }
  for (int l = threadIdx.x; l < 64 * 64; l += 256) {
    int k = l >> 6, cc = l & 63;
    int gc = c0 + cc;
    Ws[k][cc] = gc < FIN ? W[(size_t)k * FIN + gc] : 0.f;
  }
  __syncthreads();
  float c00 = 0.f, c01 = 0.f, c02 = 0.f, c03 = 0.f;
  float c10 = 0.f, c11 = 0.f, c12 = 0.f, c13 = 0.f;
  float c20 = 0.f, c21 = 0.f, c22 = 0.f, c23 = 0.f;
  float c30 = 0.f, c31 = 0.f, c32 = 0.f, c33 = 0.f;
  int ra = tr * 4, cb = tc * 4;
#pragma unroll
  for (int kk = 0; kk < 64; kk++) {
    float a0 = Ys[kk][ra + 0], a1 = Ys[kk][ra + 1];
    float a2 = Ys[kk][ra + 2], a3 = Ys[kk][ra + 3];
    float b0 = Ws[kk][cb + 0], b1 = Ws[kk][cb + 1];
    float b2 = Ws[kk][cb + 2], b3 = Ws[kk][cb + 3];
    c00 += a0 * b0; c01 += a0 * b1; c02 += a0 * b2; c03 += a0 * b3;
    c10 += a1 * b0; c11 += a1 * b1; c12 += a1 * b2; c13 += a1 * b3;
    c20 += a2 * b0; c21 += a2 * b1; c22 += a2 * b2; c23 += a2 * b3;
    c30 += a3 * b0; c31 += a3 * b1; c32 += a3 * b2; c33 += a3 * b3;
  }
  int row = row0 + ra;
  int gc0 = c0 + cb;
  // scalar stores with bounds check (last column tile is partial: 448+64>500)
  if (gc0 + 3 < FIN) {
    float b0 = bias[gc0], b1 = bias[gc0 + 1], b2 = bias[gc0 + 2], b3 = bias[gc0 + 3];
    float* p0 = &C[(size_t)row * FIN + gc0];
    p0[0] = c00 + b0; p0[1] = c01 + b1; p0[2] = c02 + b2; p0[3] = c03 + b3;
    float* p1 = p0 + FIN;
    p1[0] = c10 + b0; p1[1] = c11 + b1; p1[2] = c12 + b2; p1[3] = c13 + b3;
    float* p2 = p1 + FIN;
    p2[0] = c20 + b0; p2[1] = c21 + b1; p2[2] = c22 + b2; p2[3] = c23 + b3;
    float* p3 = p2 + FIN;
    p3[0] = c30 + b0; p3[1] = c31 + b1; p3[2] = c32 + b2; p3[3] = c33 + b3;
  } else {
    if (gc0 + 0 < FIN) { float bv = bias[gc0 + 0];
      C[(size_t)(row+0)*FIN+gc0+0]=c00+bv; C[(size_t)(row+1)*FIN+gc0+0]=c10+bv;
      C[(size_t)(row+2)*FIN+gc0+0]=c20+bv; C[(size_t)(row+3)*FIN+gc0+0]=c30+bv; }
    if (gc0 + 1 < FIN) { float bv = bias[gc0 + 1];
      C[(size_t)(row+0)*FIN+gc0+1]=c01+bv; C[(size_t)(row+1)*FIN+gc0+1]=c11+bv;
      C[(size_t)(row+2)*FIN+gc0+1]=c21+bv; C[(size_t)(row+3)*FIN+gc0+1]=c31+bv; }
    if (gc0 + 2 < FIN) { float bv = bias[gc0 + 2];
      C[(size_t)(row+0)*FIN+gc0+2]=c02+bv; C[(size_t)(row+1)*FIN+gc0+2]=c12+bv;
      C[(size_t)(row+2)*FIN+gc0+2]=c22+bv; C[(size_t)(row+3)*FIN+gc0+2]=c32+bv; }
    if (gc0 + 3 < FIN) { float bv = bias[gc0 + 3];
      C[(size_t)(row+0)*FIN+gc0+3]=c03+bv; C[(size_t)(row+1)*FIN+gc0+3]=c13+bv;
      C[(size_t)(row+2)*FIN+gc0+3]=c23+bv; C[(size_t)(row+3)*FIN+gc0+3]=c33+bv; }
  }
}

// ---------------------------------------------------------------------------

extern "C" void kernel_launch(void* const* d_in, const int* in_sizes, int n_in,
                              void* d_out, int out_size, void* d_ws, size_t ws_size,
                              hipStream_t stream) {
  const float* x      = (const float*)d_in[0];
  const float* w1     = (const float*)d_in[1];
  const float* b1     = (const float*)d_in[2];
  const float* w2     = (const float*)d_in[3];
  const float* b2     = (const float*)d_in[4];
  const float* w3     = (const float*)d_in[5];
  const float* b3     = (const float*)d_in[6];
  const float* p1wrel = (const float*)d_in[7];
  const float* p1brel = (const float*)d_in[8];
  const float* p1wroot= (const float*)d_in[9];
  const float* p2wrel = (const float*)d_in[10];
  const float* p2brel = (const float*)d_in[11];
  const float* p2wroot= (const float*)d_in[12];
  const float* p3wrel = (const float*)d_in[13];
  const float* p3brel = (const float*)d_in[14];
  const float* p3wroot= (const float*)d_in[15];
  const float* u0w    = (const float*)d_in[16];
  const float* u0b    = (const float*)d_in[17];
  const float* u1w    = (const float*)d_in[18];
  const float* u1b    = (const float*)d_in[19];
  const float* u2w    = (const float*)d_in[20];
  const float* u2b    = (const float*)d_in[21];
  const int*   ei     = (const int*)d_in[22];
  float* out = (float*)d_out;

  char* wp = (char*)d_ws;
  auto alloc = [&](size_t bytes) -> void* {
    void* p = (void*)wp;
    wp += (bytes + 255) & ~(size_t)255;
    return p;
  };
  // contiguous zero-fill span: A0b, up0, up1, up2
  unsigned* A0b  = (unsigned*)alloc((size_t)NN  * W0 * 4);
  float* up0  = (float*)alloc((size_t)KK2 * 64 * 4);
  float* up1  = (float*)alloc((size_t)KK1 * 64 * 4);
  float* up2  = (float*)alloc((size_t)NN * 64 * 4);
  char* zero_end = wp;
  unsigned* A1b  = (unsigned*)alloc((size_t)KK1 * W1 * 4);
  unsigned* A1ab = (unsigned*)alloc((size_t)KK1 * W1 * 4);
  unsigned* A2b  = (unsigned*)alloc((size_t)KK2 * W2 * 4);
  unsigned* H2b  = (unsigned*)alloc((size_t)KK2 * W2 * 4);
  float* dis0 = (float*)alloc((size_t)NN * 4);
  float* dis1 = (float*)alloc((size_t)KK1 * 4);
  float* dis2 = (float*)alloc((size_t)KK2 * 4);
  float* xw   = (float*)alloc((size_t)NN * 64 * 4);
  float* x1   = (float*)alloc((size_t)NN * 64 * 4);
  float* x2   = (float*)alloc((size_t)KK1 * 64 * 4);
  float* x3   = (float*)alloc((size_t)KK2 * 64 * 4);
  float* y0   = (float*)alloc((size_t)NN * 64 * 4);
  float* part500 = (float*)alloc((size_t)4 * NN * 64 * 4);
  float* tvec = (float*)alloc((size_t)NN * 4);
  float* rvec = (float*)alloc((size_t)NN * 4);
  float* svec = (float*)alloc((size_t)NN * 4);
  float* vals = (float*)alloc((size_t)NN * 4);
  float* part = (float*)alloc((size_t)64 * 64 * 4);
  int* rank  = (int*)alloc((size_t)NN * 4);
  int* perm1 = (int*)alloc((size_t)KK1 * 4);
  int* perm2 = (int*)alloc((size_t)KK2 * 4);
  int* perm3 = (int*)alloc((size_t)KK3 * 4);

  const int G2 = (KK2 + 63) / 64;   // colsum partial count (41)

  // ---- single zero-fill for all scattered-write buffers ----
  {
    long n4 = (long)(zero_end - (char*)A0b) / 16;
    fill4_kernel<<<2048, 256, 0, stream>>>((float4*)A0b, n4);
  }

  // ---- A0 bitset + dis0 ----
  scatter_bits_kernel<<<(EE + 255) / 256, 256, 0, stream>>>(A0b, ei);
  popcnt_dis_kernel<<<NN / 4, 256, 0, stream>>>(A0b, W0, dis0, NN);

  // ---- level 1 ----
  gemm500_kernel<<<dim3(64, 4), 256, 0, stream>>>(x, w1, part500);
  reduce4_scale_kernel<<<NN * 16 / 256, 256, 0, stream>>>(
      (const float4*)part500, dis0, (float4*)xw);
  spmm_nbr_kernel<<<NN / 4, 256, 0, stream>>>(A0b, W0, xw, nullptr, 0, dis0, b1,
      p1wrel, p1wroot, tvec, rvec, nullptr, nullptr, x1, NN, 0);
  matvec_bits_kernel<<<NN / 4, 256, 0, stream>>>(A0b, W0, tvec, rvec, p1brel, 0, svec, rank, NN);
  topk_count_kernel<<<dim3((NN + 255) / 256, (NN + 511) / 512), 256, 0, stream>>>(svec, NN, rank);
  topk_place_kernel<<<(NN + 255) / 256, 256, 0, stream>>>(svec, rank, NN, KK1, perm1, vals);
  subgraph_bits_kernel<<<KK1, 256, 0, stream>>>(A0b, W0, perm1, KK1, W1, A1b);
  augment_or_kernel<<<KK1, 128, 0, stream>>>(A1b, A1ab, nullptr, dis1, W1, KK1);

  // ---- level 2 ----
  gemm_k64x4_kernel<<<(KK1 + 15) / 16, 256, 0, stream>>>(x1, w2, perm1, vals, dis1, xw, KK1);
  spmm_nbr_kernel<<<(KK1 + 3) / 4, 256, 0, stream>>>(A1ab, W1, xw, nullptr, 0, dis1, b2,
      p2wrel, p2wroot, tvec, rvec, nullptr, nullptr, x2, KK1, 0);
  matvec_bits_kernel<<<(KK1 + 3) / 4, 256, 0, stream>>>(A1ab, W1, tvec, rvec, p2brel, 0, svec, rank, KK1);
  topk_count_kernel<<<dim3((KK1 + 255) / 256, (KK1 + 511) / 512), 256, 0, stream>>>(svec, KK1, rank);
  topk_place_kernel<<<(KK1 + 255) / 256, 256, 0, stream>>>(svec, rank, KK1, KK2, perm2, vals);
  subgraph_bits_kernel<<<KK2, 256, 0, stream>>>(A1ab, W1, perm2, KK2, W2, A2b);
  // A2a ~99.98% dense: emit only complement (holes) + dis2
  augment_or_kernel<<<KK2, 128, 0, stream>>>(A2b, nullptr, H2b, dis2, W2, KK2);

  // ---- level 3 (complement trick: A2a@B = colsum(B) - holes@B) ----
  gemm_k64x4_kernel<<<(KK2 + 15) / 16, 256, 0, stream>>>(x2, w3, perm2, vals, dis2, xw, KK2);
  colsum_part_kernel<<<G2, 256, 0, stream>>>(xw, KK2, part);
  spmm_nbr_kernel<<<(KK2 + 3) / 4, 256, 0, stream>>>(H2b, W2, xw, part, G2, dis2, b3,
      p3wrel, p3wroot, tvec, rvec, nullptr, nullptr, x3, KK2, 0);
  matvec_bits_kernel<<<(KK2 + 3) / 4, 256, 0, stream>>>(H2b, W2, tvec, rvec, p3brel, 1, svec, rank, KK2);
  topk_count_kernel<<<dim3((KK2 + 255) / 256, (KK2 + 511) / 512), 256, 0, stream>>>(svec, KK2, rank);
  topk_place_kernel<<<(KK2 + 255) / 256, 256, 0, stream>>>(svec, rank, KK2, KK3, perm3, vals);
  scatter_gate_kernel<<<(KK3 + 3) / 4, 256, 0, stream>>>(x3, perm3, vals, dis2, up0, KK3);

  // ---- decoder ----
  gemm_k64x4_kernel<<<(KK2 + 15) / 16, 256, 0, stream>>>(up0, u0w, nullptr, nullptr, nullptr, xw, KK2);
  colsum_part_kernel<<<G2, 256, 0, stream>>>(xw, KK2, part);
  spmm_nbr_kernel<<<(KK2 + 3) / 4, 256, 0, stream>>>(H2b, W2, xw, part, G2, dis2, u0b,
      nullptr, nullptr, nullptr, nullptr, perm2, dis1, up1, KK2, 1);

  gemm_k64x4_kernel<<<(KK1 + 15) / 16, 256, 0, stream>>>(up1, u1w, nullptr, nullptr, nullptr, xw, KK1);
  spmm_nbr_kernel<<<(KK1 + 3) / 4, 256, 0, stream>>>(A1ab, W1, xw, nullptr, 0, dis1, u1b,
      nullptr, nullptr, nullptr, nullptr, perm1, dis0, up2, KK1, 1);

  // final GCN reassociated: out = (dis0 .* (A0 @ up2)) @ u2w + u2b
  spmm_nbr_kernel<<<NN / 4, 256, 0, stream>>>(A0b, W0, up2, nullptr, 0, dis0, nullptr,
      nullptr, nullptr, nullptr, nullptr, nullptr, nullptr, y0, NN, 0);
  gemm_wide_tile_kernel<<<dim3(64, 8), 256, 0, stream>>>(y0, u2w, u2b, out);
}